// Round 8
// baseline (305.467 us; speedup 1.0000x reference)
//
#include <hip/hip_runtime.h>
#include <stdint.h>

#define NB 8
#define NN 2048
#define FF 128
#define ALPHA 0.2f

typedef unsigned short u16;
typedef __attribute__((ext_vector_type(8))) short bf16x8;  // 8 bf16, 4 VGPRs
typedef __attribute__((ext_vector_type(4))) float f32x4;

__device__ __forceinline__ float bf2f(u16 h) {
    union { uint32_t u; float f; } v; v.u = ((uint32_t)h) << 16; return v.f;
}
__device__ __forceinline__ u16 f2bf(float x) {
    union { float f; uint32_t u; } v; v.f = x;
    uint32_t r = v.u + 0x7fffu + ((v.u >> 16) & 1u);  // RNE
    return (u16)(r >> 16);
}
__device__ __forceinline__ uint4 pack8(const float o[8]) {
    uint4 r;
    r.x = (uint32_t)f2bf(o[0]) | ((uint32_t)f2bf(o[1]) << 16);
    r.y = (uint32_t)f2bf(o[2]) | ((uint32_t)f2bf(o[3]) << 16);
    r.z = (uint32_t)f2bf(o[4]) | ((uint32_t)f2bf(o[5]) << 16);
    r.w = (uint32_t)f2bf(o[6]) | ((uint32_t)f2bf(o[7]) << 16);
    return r;
}
__device__ __forceinline__ void load8f(const float* p, size_t i, float o[8]) {
    float4 a = *(const float4*)(p + i);
    float4 b = *(const float4*)(p + i + 4);
    o[0]=a.x; o[1]=a.y; o[2]=a.z; o[3]=a.w;
    o[4]=b.x; o[5]=b.y; o[6]=b.z; o[7]=b.w;
}

// ---------------------------------------------------------------------------
// Kernel 1 (unchanged from R7, validated): h = x·W^T via MFMA -> hT[b][o][n]
// bf16 (LDS-bounced, coalesced); src/dst = x·(W^T a) in fp32 during staging.
// ---------------------------------------------------------------------------
__global__ __launch_bounds__(256) void k_prep(
    const float* __restrict__ x,    // [B][N][F]
    const float* __restrict__ w,    // [F][F] o-major
    const float* __restrict__ as_,  // [F]
    const float* __restrict__ ad_,  // [F]
    u16* __restrict__ hT,           // [B][F][N] bf16
    float* __restrict__ srcp, float* __restrict__ dstp)
{
    __shared__ __attribute__((aligned(16))) u16 Ws[128][136];   // also bounce buf
    __shared__ __attribute__((aligned(16))) u16 Xs[64][136];
    __shared__ float waS[128], waD[128];
    __shared__ float lredS[64][4], lredD[64][4];

    const int b  = blockIdx.x >> 5;
    const int n0 = (blockIdx.x & 31) * 64;
    const int t  = threadIdx.x;
    const int wv = t >> 6, lane = t & 63, quad = lane >> 4, lr = lane & 15;

    {
        const int o = t >> 1, fb = (t & 1) * 64;
        #pragma unroll
        for (int k = 0; k < 8; ++k) {
            float v8[8];
            load8f(w, (size_t)o * FF + fb + k * 8, v8);
            *(uint4*)&Ws[o][fb + k * 8] = pack8(v8);
        }
    }
    if (t < 128) {
        float s = 0.f;
        for (int o = 0; o < FF; ++o) s += w[(size_t)o * FF + t] * as_[o];
        waS[t] = s;
    } else {
        const int f = t - 128;
        float s = 0.f;
        for (int o = 0; o < FF; ++o) s += w[(size_t)o * FF + f] * ad_[o];
        waD[f] = s;
    }
    __syncthreads();

    {
        const int r = t >> 2, q = t & 3;
        float sp = 0.f, dp = 0.f;
        #pragma unroll
        for (int k = 0; k < 4; ++k) {
            float v8[8];
            load8f(x, (size_t)(b * NN + n0 + r) * FF + q * 32 + k * 8, v8);
            *(uint4*)&Xs[r][q * 32 + k * 8] = pack8(v8);
            #pragma unroll
            for (int u = 0; u < 8; ++u) {
                sp += v8[u] * waS[q * 32 + k * 8 + u];
                dp += v8[u] * waD[q * 32 + k * 8 + u];
            }
        }
        lredS[r][q] = sp; lredD[r][q] = dp;
    }
    __syncthreads();
    if (t < 64) {
        srcp[b * NN + n0 + t] = lredS[t][0] + lredS[t][1] + lredS[t][2] + lredS[t][3];
        dstp[b * NN + n0 + t] = lredD[t][0] + lredD[t][1] + lredD[t][2] + lredD[t][3];
    }

    f32x4 hacc[8] = {};
    #pragma unroll
    for (int kc = 0; kc < 4; ++kc) {
        const int ko = kc * 32 + quad * 8;
        bf16x8 a = *(const bf16x8*)&Xs[wv * 16 + lr][ko];
        #pragma unroll
        for (int t8 = 0; t8 < 8; ++t8) {
            bf16x8 bb = *(const bf16x8*)&Ws[t8 * 16 + lr][ko];
            hacc[t8] = __builtin_amdgcn_mfma_f32_16x16x32_bf16(a, bb, hacc[t8], 0, 0, 0);
        }
    }
    __syncthreads();

    u16* HsB = &Ws[0][0];
    #pragma unroll
    for (int t8 = 0; t8 < 8; ++t8) {
        #pragma unroll
        for (int reg = 0; reg < 4; ++reg)
            HsB[(t8 * 16 + lr) * 68 + wv * 16 + quad * 4 + reg] = f2bf(hacc[t8][reg]);
    }
    __syncthreads();
    {
        const int r16 = t >> 4, ng = t & 15;
        #pragma unroll
        for (int s = 0; s < 8; ++s) {
            const int o = s * 16 + r16;
            uint2 v = *(const uint2*)&HsB[o * 68 + ng * 4];
            *(uint2*)&hT[(size_t)(b * FF + o) * NN + n0 + ng * 4] = v;
        }
    }
}

// ---------------------------------------------------------------------------
// Kernel 2: attention, restructured. 512 blocks = 8 b x 64 i-tiles(32);
// 256 threads = 4 waves. ONE barrier per j-iter:
//  - adj register double-buffer, prefetched one 128-j tile ahead (HBM latency
//    hidden behind the P-gen phase before the barrier's vmcnt drain)
//  - dst preloaded once to LDS (8 KB)
//  - PV B-fragments read DIRECTLY from hT global (o-major => 16 B contiguous
//    per fragment, L2-resident 512 KB/batch) — no Hs staging, no 2nd barrier
//  - Ps double-buffered (2 x 32 x 136 bf16)
// Numerics: operation-identical to R7 (same order) -> bit-identical output.
// ---------------------------------------------------------------------------
__global__ __launch_bounds__(256, 2) void k_attn(
    const int*   __restrict__ adj,   // [B][N][N]
    const u16*   __restrict__ hT,    // [B][F][N] bf16
    const float* __restrict__ srcp,
    const float* __restrict__ dstp,
    float* __restrict__ out)         // [B][N][F] fp32
{
    __shared__ __attribute__((aligned(16))) u16 Ps[2][32][136];  // 17408 B
    __shared__ __attribute__((aligned(16))) float dstAll[2048];  //  8192 B
    __shared__ float lred[32][8];
    __shared__ float lrow[32];

    const int b  = blockIdx.x >> 6;
    const int i0 = (blockIdx.x & 63) * 32;
    const int t  = threadIdx.x;
    const int wv = t >> 6, lane = t & 63, quad = lane >> 4, lr = lane & 15;
    const int rowt = (wv & 1) * 16, colt = (wv >> 1) * 64;

    const int il = t >> 3, q = t & 7;            // P-gen: row il, 16 j's at q*16
    const float src_i  = srcp[b * NN + i0 + il];
    const int*  adjrow = adj + (size_t)(b * NN + i0 + il) * NN;
    const u16*  hTb    = hT + (size_t)b * FF * NN;

    // prologue: dst -> LDS (whole batch row, reused by all 16 iters)
    {
        const float* dp = dstp + b * NN;
        *(float4*)&dstAll[t * 8]     = *(const float4*)(dp + t * 8);
        *(float4*)&dstAll[t * 8 + 4] = *(const float4*)(dp + t * 8 + 4);
    }
    // prologue: adj tile 0 into register buffer 0
    int4 areg[2][4];
    #pragma unroll
    for (int it = 0; it < 4; ++it)
        areg[0][it] = *(const int4*)(adjrow + q * 16 + it * 4);
    __syncthreads();

    f32x4 acc[4] = {};
    float lacc = 0.f;

    for (int k = 0; k < 16; ++k) {
        const int j0 = k << 7, pb = k & 1;

        // prefetch adj tile k+1 (in flight across P-gen; drained at barrier)
        if (k < 15) {
            #pragma unroll
            for (int it = 0; it < 4; ++it)
                areg[pb ^ 1][it] = *(const int4*)(adjrow + j0 + 128 + q * 16 + it * 4);
        }

        // P-gen: thread (il, q) covers j = j0 + q*16 .. +16
        u16 pv16[16];
        #pragma unroll
        for (int it = 0; it < 4; ++it) {
            const int4 a4 = areg[pb][it];
            const int* ai = (const int*)&a4;
            float4 d4 = *(const float4*)&dstAll[j0 + q * 16 + it * 4];
            const float* dv = (const float*)&d4;
            #pragma unroll
            for (int u = 0; u < 4; ++u) {
                float e = src_i + dv[u];
                e = e > 0.f ? e : ALPHA * e;
                float p = __expf(e);
                p = (ai[u] > 0) ? p : 0.f;
                const u16 pvb = f2bf(p);
                pv16[it * 4 + u] = pvb;
                lacc += bf2f(pvb);              // denom == numerator's P exactly
            }
        }
        uint4 w0, w1;
        w0.x = (uint32_t)pv16[0]  | ((uint32_t)pv16[1]  << 16);
        w0.y = (uint32_t)pv16[2]  | ((uint32_t)pv16[3]  << 16);
        w0.z = (uint32_t)pv16[4]  | ((uint32_t)pv16[5]  << 16);
        w0.w = (uint32_t)pv16[6]  | ((uint32_t)pv16[7]  << 16);
        w1.x = (uint32_t)pv16[8]  | ((uint32_t)pv16[9]  << 16);
        w1.y = (uint32_t)pv16[10] | ((uint32_t)pv16[11] << 16);
        w1.z = (uint32_t)pv16[12] | ((uint32_t)pv16[13] << 16);
        w1.w = (uint32_t)pv16[14] | ((uint32_t)pv16[15] << 16);
        *(uint4*)&Ps[pb][il][q * 16]     = w0;
        *(uint4*)&Ps[pb][il][q * 16 + 8] = w1;

        __syncthreads();   // Ps[pb] visible (and prev PV of Ps[pb] long done)

        // PV: A from Ps[pb] (LDS), B directly from hT global (L2-resident)
        const u16* hTj = hTb + j0;
        #pragma unroll
        for (int kc = 0; kc < 4; ++kc) {
            const int ko = kc * 32 + quad * 8;
            bf16x8 a = *(const bf16x8*)&Ps[pb][rowt + lr][ko];
            #pragma unroll
            for (int t8 = 0; t8 < 4; ++t8) {
                bf16x8 bb = *(const bf16x8*)(hTj + (size_t)(colt + t8 * 16 + lr) * NN + ko);
                acc[t8] = __builtin_amdgcn_mfma_f32_16x16x32_bf16(a, bb, acc[t8], 0, 0, 0);
            }
        }
        // no 2nd barrier: next iter writes Ps[pb^1]; slow waves still reading
        // Ps[pb] are disjoint from it, and barrier k+1 orders the k+2 reuse.
    }

    lred[il][q] = lacc;
    __syncthreads();
    if (t < 32) {
        float s = 0.f;
        #pragma unroll
        for (int kk = 0; kk < 8; ++kk) s += lred[t][kk];
        lrow[t] = s;
    }
    __syncthreads();

    // epilogue: normalize, ELU, fp32 store
    #pragma unroll
    for (int t8 = 0; t8 < 4; ++t8) {
        const int col = colt + t8 * 16 + lr;
        #pragma unroll
        for (int reg = 0; reg < 4; ++reg) {
            const int row = rowt + quad * 4 + reg;
            const float l = fmaxf(lrow[row], 1e-30f);
            float v = acc[t8][reg] / l;
            v = v > 0.f ? v : __expf(v) - 1.f;
            out[(size_t)(b * NN + i0 + row) * FF + col] = v;
        }
    }
}

// ---------------------------------------------------------------------------
extern "C" void kernel_launch(void* const* d_in, const int* in_sizes, int n_in,
                              void* d_out, int out_size, void* d_ws, size_t ws_size,
                              hipStream_t stream) {
    const float* x = nullptr; const int* adj = nullptr; const float* w = nullptr;
    const float* as_ = nullptr; const float* ad_ = nullptr;
    for (int i = 0; i < n_in; ++i) {
        const long long s = in_sizes[i];
        if      (s == (long long)NB * NN * FF)  x   = (const float*)d_in[i];
        else if (s == (long long)NB * NN * NN)  adj = (const int*)d_in[i];
        else if (s == FF * FF)                  w   = (const float*)d_in[i];
        else if (s == FF) { if (!as_) as_ = (const float*)d_in[i]; else ad_ = (const float*)d_in[i]; }
    }
    if (!x)   x   = (const float*)d_in[0];
    if (!adj) adj = (const int*)d_in[1];
    if (!w)   w   = (const float*)d_in[2];
    if (!as_) as_ = (const float*)d_in[3];
    if (!ad_) ad_ = (const float*)d_in[4];
    float* out = (float*)d_out;

    u16*   hT   = (u16*)d_ws;                              // 4 MiB
    float* srcp = (float*)((char*)d_ws + (size_t)NB * FF * NN * sizeof(u16));
    float* dstp = srcp + NB * NN;                          // 64 KiB each

    k_prep<<<256, 256, 0, stream>>>(x, w, as_, ad_, hT, srcp, dstp);
    k_attn<<<512, 256, 0, stream>>>(adj, hT, srcp, dstp, out);
}

// Round 9
// 269.251 us; speedup vs baseline: 1.1345x; 1.1345x over previous
//
#include <hip/hip_runtime.h>
#include <stdint.h>

#define NB 8
#define NN 2048
#define FF 128
#define ALPHA 0.2f

typedef unsigned short u16;
typedef __attribute__((ext_vector_type(8))) short bf16x8;  // 8 bf16, 4 VGPRs
typedef __attribute__((ext_vector_type(4))) float f32x4;

__device__ __forceinline__ float bf2f(u16 h) {
    union { uint32_t u; float f; } v; v.u = ((uint32_t)h) << 16; return v.f;
}
__device__ __forceinline__ u16 f2bf(float x) {
    union { float f; uint32_t u; } v; v.f = x;
    uint32_t r = v.u + 0x7fffu + ((v.u >> 16) & 1u);  // RNE
    return (u16)(r >> 16);
}
__device__ __forceinline__ uint4 pack8(const float o[8]) {
    uint4 r;
    r.x = (uint32_t)f2bf(o[0]) | ((uint32_t)f2bf(o[1]) << 16);
    r.y = (uint32_t)f2bf(o[2]) | ((uint32_t)f2bf(o[3]) << 16);
    r.z = (uint32_t)f2bf(o[4]) | ((uint32_t)f2bf(o[5]) << 16);
    r.w = (uint32_t)f2bf(o[6]) | ((uint32_t)f2bf(o[7]) << 16);
    return r;
}
__device__ __forceinline__ void load8f(const float* p, size_t i, float o[8]) {
    float4 a = *(const float4*)(p + i);
    float4 b = *(const float4*)(p + i + 4);
    o[0]=a.x; o[1]=a.y; o[2]=a.z; o[3]=a.w;
    o[4]=b.x; o[5]=b.y; o[6]=b.z; o[7]=b.w;
}

// ---------------------------------------------------------------------------
// Kernel 1 (validated since R7): h = x·W^T via MFMA -> hT[b][o][n] bf16
// (LDS-bounced, coalesced); src/dst = x·(W^T a) in fp32 during staging.
// ---------------------------------------------------------------------------
__global__ __launch_bounds__(256) void k_prep(
    const float* __restrict__ x,    // [B][N][F]
    const float* __restrict__ w,    // [F][F] o-major
    const float* __restrict__ as_,  // [F]
    const float* __restrict__ ad_,  // [F]
    u16* __restrict__ hT,           // [B][F][N] bf16
    float* __restrict__ srcp, float* __restrict__ dstp)
{
    __shared__ __attribute__((aligned(16))) u16 Ws[128][136];   // also bounce buf
    __shared__ __attribute__((aligned(16))) u16 Xs[64][136];
    __shared__ float waS[128], waD[128];
    __shared__ float lredS[64][4], lredD[64][4];

    const int b  = blockIdx.x >> 5;
    const int n0 = (blockIdx.x & 31) * 64;
    const int t  = threadIdx.x;
    const int wv = t >> 6, lane = t & 63, quad = lane >> 4, lr = lane & 15;

    {
        const int o = t >> 1, fb = (t & 1) * 64;
        #pragma unroll
        for (int k = 0; k < 8; ++k) {
            float v8[8];
            load8f(w, (size_t)o * FF + fb + k * 8, v8);
            *(uint4*)&Ws[o][fb + k * 8] = pack8(v8);
        }
    }
    if (t < 128) {
        float s = 0.f;
        for (int o = 0; o < FF; ++o) s += w[(size_t)o * FF + t] * as_[o];
        waS[t] = s;
    } else {
        const int f = t - 128;
        float s = 0.f;
        for (int o = 0; o < FF; ++o) s += w[(size_t)o * FF + f] * ad_[o];
        waD[f] = s;
    }
    __syncthreads();

    {
        const int r = t >> 2, q = t & 3;
        float sp = 0.f, dp = 0.f;
        #pragma unroll
        for (int k = 0; k < 4; ++k) {
            float v8[8];
            load8f(x, (size_t)(b * NN + n0 + r) * FF + q * 32 + k * 8, v8);
            *(uint4*)&Xs[r][q * 32 + k * 8] = pack8(v8);
            #pragma unroll
            for (int u = 0; u < 8; ++u) {
                sp += v8[u] * waS[q * 32 + k * 8 + u];
                dp += v8[u] * waD[q * 32 + k * 8 + u];
            }
        }
        lredS[r][q] = sp; lredD[r][q] = dp;
    }
    __syncthreads();
    if (t < 64) {
        srcp[b * NN + n0 + t] = lredS[t][0] + lredS[t][1] + lredS[t][2] + lredS[t][3];
        dstp[b * NN + n0 + t] = lredD[t][0] + lredD[t][1] + lredD[t][2] + lredD[t][3];
    }

    f32x4 hacc[8] = {};
    #pragma unroll
    for (int kc = 0; kc < 4; ++kc) {
        const int ko = kc * 32 + quad * 8;
        bf16x8 a = *(const bf16x8*)&Xs[wv * 16 + lr][ko];
        #pragma unroll
        for (int t8 = 0; t8 < 8; ++t8) {
            bf16x8 bb = *(const bf16x8*)&Ws[t8 * 16 + lr][ko];
            hacc[t8] = __builtin_amdgcn_mfma_f32_16x16x32_bf16(a, bb, hacc[t8], 0, 0, 0);
        }
    }
    __syncthreads();

    u16* HsB = &Ws[0][0];
    #pragma unroll
    for (int t8 = 0; t8 < 8; ++t8) {
        #pragma unroll
        for (int reg = 0; reg < 4; ++reg)
            HsB[(t8 * 16 + lr) * 68 + wv * 16 + quad * 4 + reg] = f2bf(hacc[t8][reg]);
    }
    __syncthreads();
    {
        const int r16 = t >> 4, ng = t & 15;
        #pragma unroll
        for (int s = 0; s < 8; ++s) {
            const int o = s * 16 + r16;
            uint2 v = *(const uint2*)&HsB[o * 68 + ng * 4];
            *(uint2*)&hT[(size_t)(b * FF + o) * NN + n0 + ng * 4] = v;
        }
    }
}

// ---------------------------------------------------------------------------
// Kernel 2: attention. Same structure as R8 but the adj double-buffer uses
// two STATICALLY-NAMED register arrays (aregA/aregB) via a 2x-unrolled
// j-loop — no dynamically-indexed private arrays (R8's pb-indexed areg[2][4]
// was demoted to scratch: VGPR=40, 115 MB phantom WRITE_SIZE, 2.3x slower).
// One barrier per 128-j tile; PV B-frags read directly from hT global
// (o-major => 16 B contiguous per fragment, L2-resident).
// ---------------------------------------------------------------------------
__device__ __forceinline__ void pgen_store(
    const int4 areg[4], const float* __restrict__ dstAll, int j0, int q,
    float src_i, float& lacc, u16* __restrict__ PsRow)
{
    u16 pv16[16];
    #pragma unroll
    for (int it = 0; it < 4; ++it) {
        const int4 a4 = areg[it];
        const int* ai = (const int*)&a4;
        float4 d4 = *(const float4*)&dstAll[j0 + q * 16 + it * 4];
        const float* dv = (const float*)&d4;
        #pragma unroll
        for (int u = 0; u < 4; ++u) {
            float e = src_i + dv[u];
            e = e > 0.f ? e : ALPHA * e;
            float p = __expf(e);
            p = (ai[u] > 0) ? p : 0.f;
            const u16 pvb = f2bf(p);
            pv16[it * 4 + u] = pvb;
            lacc += bf2f(pvb);                 // denom == numerator's P exactly
        }
    }
    uint4 w0, w1;
    w0.x = (uint32_t)pv16[0]  | ((uint32_t)pv16[1]  << 16);
    w0.y = (uint32_t)pv16[2]  | ((uint32_t)pv16[3]  << 16);
    w0.z = (uint32_t)pv16[4]  | ((uint32_t)pv16[5]  << 16);
    w0.w = (uint32_t)pv16[6]  | ((uint32_t)pv16[7]  << 16);
    w1.x = (uint32_t)pv16[8]  | ((uint32_t)pv16[9]  << 16);
    w1.y = (uint32_t)pv16[10] | ((uint32_t)pv16[11] << 16);
    w1.z = (uint32_t)pv16[12] | ((uint32_t)pv16[13] << 16);
    w1.w = (uint32_t)pv16[14] | ((uint32_t)pv16[15] << 16);
    *(uint4*)(PsRow + q * 16)     = w0;
    *(uint4*)(PsRow + q * 16 + 8) = w1;
}

__global__ __launch_bounds__(256, 2) void k_attn(
    const int*   __restrict__ adj,   // [B][N][N]
    const u16*   __restrict__ hT,    // [B][F][N] bf16
    const float* __restrict__ srcp,
    const float* __restrict__ dstp,
    float* __restrict__ out)         // [B][N][F] fp32
{
    __shared__ __attribute__((aligned(16))) u16 Ps0[32][136];
    __shared__ __attribute__((aligned(16))) u16 Ps1[32][136];
    __shared__ __attribute__((aligned(16))) float dstAll[2048];
    __shared__ float lred[32][8];
    __shared__ float lrow[32];

    const int b  = blockIdx.x >> 6;
    const int i0 = (blockIdx.x & 63) * 32;
    const int t  = threadIdx.x;
    const int wv = t >> 6, lane = t & 63, quad = lane >> 4, lr = lane & 15;
    const int rowt = (wv & 1) * 16, colt = (wv >> 1) * 64;

    const int il = t >> 3, q = t & 7;            // P-gen: row il, 16 j's at q*16
    const float src_i  = srcp[b * NN + i0 + il];
    const int*  adjrow = adj + (size_t)(b * NN + i0 + il) * NN;
    const u16*  hTb    = hT + (size_t)b * FF * NN;

    {   // dst -> LDS once
        const float* dp = dstp + b * NN;
        *(float4*)&dstAll[t * 8]     = *(const float4*)(dp + t * 8);
        *(float4*)&dstAll[t * 8 + 4] = *(const float4*)(dp + t * 8 + 4);
    }
    int4 aregA[4], aregB[4];
    #pragma unroll
    for (int it = 0; it < 4; ++it)
        aregA[it] = *(const int4*)(adjrow + q * 16 + it * 4);
    __syncthreads();

    f32x4 acc[4] = {};
    float lacc = 0.f;

    #pragma unroll 1
    for (int k = 0; k < 16; k += 2) {
        // ---- even tile k: use aregA, prefetch k+1 into aregB
        {
            const int j0 = k << 7;
            #pragma unroll
            for (int it = 0; it < 4; ++it)
                aregB[it] = *(const int4*)(adjrow + j0 + 128 + q * 16 + it * 4);
            pgen_store(aregA, dstAll, j0, q, src_i, lacc, &Ps0[il][0]);
            __syncthreads();
            const u16* hTj = hTb + j0;
            #pragma unroll
            for (int kc = 0; kc < 4; ++kc) {
                const int ko = kc * 32 + quad * 8;
                bf16x8 a = *(const bf16x8*)&Ps0[rowt + lr][ko];
                #pragma unroll
                for (int t8 = 0; t8 < 4; ++t8) {
                    bf16x8 bb = *(const bf16x8*)(hTj + (size_t)(colt + t8 * 16 + lr) * NN + ko);
                    acc[t8] = __builtin_amdgcn_mfma_f32_16x16x32_bf16(a, bb, acc[t8], 0, 0, 0);
                }
            }
        }
        // ---- odd tile k+1: use aregB, prefetch k+2 into aregA
        {
            const int j0 = (k + 1) << 7;
            if (k + 2 < 16) {
                #pragma unroll
                for (int it = 0; it < 4; ++it)
                    aregA[it] = *(const int4*)(adjrow + j0 + 128 + q * 16 + it * 4);
            }
            pgen_store(aregB, dstAll, j0, q, src_i, lacc, &Ps1[il][0]);
            __syncthreads();
            const u16* hTj = hTb + j0;
            #pragma unroll
            for (int kc = 0; kc < 4; ++kc) {
                const int ko = kc * 32 + quad * 8;
                bf16x8 a = *(const bf16x8*)&Ps1[rowt + lr][ko];
                #pragma unroll
                for (int t8 = 0; t8 < 4; ++t8) {
                    bf16x8 bb = *(const bf16x8*)(hTj + (size_t)(colt + t8 * 16 + lr) * NN + ko);
                    acc[t8] = __builtin_amdgcn_mfma_f32_16x16x32_bf16(a, bb, acc[t8], 0, 0, 0);
                }
            }
        }
    }

    lred[il][q] = lacc;
    __syncthreads();
    if (t < 32) {
        float s = 0.f;
        #pragma unroll
        for (int kk = 0; kk < 8; ++kk) s += lred[t][kk];
        lrow[t] = s;
    }
    __syncthreads();

    #pragma unroll
    for (int t8 = 0; t8 < 4; ++t8) {
        const int col = colt + t8 * 16 + lr;
        #pragma unroll
        for (int reg = 0; reg < 4; ++reg) {
            const int row = rowt + quad * 4 + reg;
            const float l = fmaxf(lrow[row], 1e-30f);
            float v = acc[t8][reg] / l;
            v = v > 0.f ? v : __expf(v) - 1.f;
            out[(size_t)(b * NN + i0 + row) * FF + col] = v;
        }
    }
}

// ---------------------------------------------------------------------------
extern "C" void kernel_launch(void* const* d_in, const int* in_sizes, int n_in,
                              void* d_out, int out_size, void* d_ws, size_t ws_size,
                              hipStream_t stream) {
    const float* x = nullptr; const int* adj = nullptr; const float* w = nullptr;
    const float* as_ = nullptr; const float* ad_ = nullptr;
    for (int i = 0; i < n_in; ++i) {
        const long long s = in_sizes[i];
        if      (s == (long long)NB * NN * FF)  x   = (const float*)d_in[i];
        else if (s == (long long)NB * NN * NN)  adj = (const int*)d_in[i];
        else if (s == FF * FF)                  w   = (const float*)d_in[i];
        else if (s == FF) { if (!as_) as_ = (const float*)d_in[i]; else ad_ = (const float*)d_in[i]; }
    }
    if (!x)   x   = (const float*)d_in[0];
    if (!adj) adj = (const int*)d_in[1];
    if (!w)   w   = (const float*)d_in[2];
    if (!as_) as_ = (const float*)d_in[3];
    if (!ad_) ad_ = (const float*)d_in[4];
    float* out = (float*)d_out;

    u16*   hT   = (u16*)d_ws;                              // 4 MiB
    float* srcp = (float*)((char*)d_ws + (size_t)NB * FF * NN * sizeof(u16));
    float* dstp = srcp + NB * NN;                          // 64 KiB each

    k_prep<<<256, 256, 0, stream>>>(x, w, as_, ad_, hT, srcp, dstp);
    k_attn<<<512, 256, 0, stream>>>(adj, hT, srcp, dstp, out);
}